// Round 3
// baseline (143.086 us; speedup 1.0000x reference)
//
#include <hip/hip_runtime.h>
#include <stdint.h>

#define Bsz 16384
#define Hh  512
#define Kd  1024      // I + H
#define BM  256       // M rows per workgroup
#define BNJ 32        // j columns per workgroup (x5 gates)
#define BK  64        // K per tile
#define NT  16        // K tiles

typedef __attribute__((ext_vector_type(8))) short bf16x8;
typedef __attribute__((ext_vector_type(4))) float f32x4;
typedef __attribute__((ext_vector_type(8))) unsigned short u16x8;

__device__ __forceinline__ unsigned short f2bf(float f) {
    union { float f; unsigned u; } v; v.f = f;
    unsigned u = v.u;
    return (unsigned short)((u + 0x7fffu + ((u >> 16) & 1u)) >> 16);
}
__device__ __forceinline__ float fast_tanh(float x) {
    float e = __expf(2.f * x);
    return (e - 1.f) / (e + 1.f);
}
__device__ __forceinline__ float fast_sigmoid(float x) {
    return 1.f / (1.f + __expf(-x));
}

// ---------------- pack A = [x | h_prev] -> bf16 [16384][1024] ----------------
__global__ void pack_A(const float* __restrict__ x, const float* __restrict__ h,
                       unsigned short* __restrict__ A) {
    const long total = (long)Bsz * Kd / 8;
    for (long i = (long)blockIdx.x * blockDim.x + threadIdx.x; i < total;
         i += (long)gridDim.x * blockDim.x) {
        long row = i >> 7;
        int  col = ((int)(i & 127)) << 3;
        const float* src = (col < 512) ? (x + row * 512 + col)
                                       : (h + row * 512 + (col - 512));
        float4 f0 = *(const float4*)(src);
        float4 f1 = *(const float4*)(src + 4);
        u16x8 o;
        o[0]=f2bf(f0.x); o[1]=f2bf(f0.y); o[2]=f2bf(f0.z); o[3]=f2bf(f0.w);
        o[4]=f2bf(f1.x); o[5]=f2bf(f1.y); o[6]=f2bf(f1.z); o[7]=f2bf(f1.w);
        *(u16x8*)(A + (i << 3)) = o;
    }
}

// ---- pack B into per-wave-fragment-linear layout ----
// block blk = ((jgrp*5 + g)*16 + kt)*2 + kh   (jgrp<32, g<5, kt<16, kh<2)
// elem  blk*512 + l*8 + e  =  W[g][ j = jgrp*16 + (l&15) ][ k = kt*64 + kh*32 + (l>>4)*8 + e ]
__global__ void pack_B(const float* __restrict__ Wxi, const float* __restrict__ Whi,
                       const float* __restrict__ Wxf, const float* __restrict__ Whf,
                       const float* __restrict__ Wxc, const float* __restrict__ Whc,
                       const float* __restrict__ Wxo, const float* __restrict__ Who,
                       const float* __restrict__ We,
                       const float* __restrict__ bxi, const float* __restrict__ bhi,
                       const float* __restrict__ bxf, const float* __restrict__ bhf,
                       const float* __restrict__ bxc, const float* __restrict__ bhc,
                       const float* __restrict__ bxo, const float* __restrict__ bho,
                       const float* __restrict__ be,
                       unsigned short* __restrict__ Bp, float* __restrict__ bias) {
    const long id = (long)blockIdx.x * blockDim.x + threadIdx.x;  // 327680 total
    if (id < 327680) {
        int blk = (int)(id >> 6);
        int l   = (int)(id & 63);
        int kh  = blk & 1;
        int kt  = (blk >> 1) & 15;
        int rest = blk >> 5;
        int g    = rest % 5;
        int jgrp = rest / 5;
        int j  = jgrp * 16 + (l & 15);
        int k0 = kt * 64 + kh * 32 + ((l >> 4) << 3);
        const float* src;
        if (g == 4) {
            src = We + (long)j * 1024 + k0;
        } else {
            const float* Wx = (g == 0) ? Wxi : (g == 1) ? Wxf : (g == 2) ? Wxc : Wxo;
            const float* Wh = (g == 0) ? Whi : (g == 1) ? Whf : (g == 2) ? Whc : Who;
            src = (k0 < 512) ? (Wx + (long)j * 512 + k0)
                             : (Wh + (long)j * 512 + (k0 - 512));
        }
        float4 f0 = *(const float4*)(src);
        float4 f1 = *(const float4*)(src + 4);
        u16x8 o;
        o[0]=f2bf(f0.x); o[1]=f2bf(f0.y); o[2]=f2bf(f0.z); o[3]=f2bf(f0.w);
        o[4]=f2bf(f1.x); o[5]=f2bf(f1.y); o[6]=f2bf(f1.z); o[7]=f2bf(f1.w);
        *(u16x8*)(Bp + (long)blk * 512 + l * 8) = o;
    }
    if (id < 2560) {
        int row = (int)id;
        int g = row >> 9, j = row & 511;
        float b;
        if (g == 4) b = be[j];
        else {
            const float* bx = (g == 0) ? bxi : (g == 1) ? bxf : (g == 2) ? bxc : bxo;
            const float* bh = (g == 0) ? bhi : (g == 1) ? bhf : (g == 2) ? bhc : bho;
            b = bx[j] + bh[j];
        }
        bias[row] = b;
    }
}

// ---------------- fused GEMM (5-gate), 4-phase/K-tile counted-vmcnt schedule ----------------
#define GL16(g, l) __builtin_amdgcn_global_load_lds( \
    (const __attribute__((address_space(1))) unsigned int*)(g), \
    (__attribute__((address_space(3))) unsigned int*)(l), 16, 0, 0)

#define WAITVM_I(n) asm volatile("s_waitcnt vmcnt(" #n ")" ::: "memory")
#define WAITVM(n) WAITVM_I(n)
#define WAITLGKM0() asm volatile("s_waitcnt lgkmcnt(0)" ::: "memory")
#define BARRIER() asm volatile("s_barrier" ::: "memory")

#define MF(a, b, c) __builtin_amdgcn_mfma_f32_16x16x32_bf16(a, b, c, 0, 0, 0)

// one B-fragment register load: reg R = g*2+kh of tile T (for next tile)
#define LB(BN, T, R) asm volatile("global_load_dwordx4 %0, %1, off" \
    : "=v"(BN[R]) : "v"(bbase + (long)(T) * 1024 + ((R) >> 1) * 16384 + ((R) & 1) * 512))
#define LBA(BN, T) do { LB(BN, T, 0); LB(BN, T, 2); LB(BN, T, 4); } while (0)
#define LBB(BN, T) do { LB(BN, T, 6); LB(BN, T, 8); LB(BN, T, 1); } while (0)
#define LBC(BN, T) do { LB(BN, T, 3); LB(BN, T, 5); } while (0)
#define LBD(BN, T) do { LB(BN, T, 7); LB(BN, T, 9); } while (0)
#define NOB() ((void)0)

// one GL16 staging chunk: phase P of A-tile T into LDS buffer SB
#define SGL(SB, T, P) GL16(A + srcoff + (P) * 65536 + (long)(T) * 64, \
                           &Alds[SB][(P) * 4096 + tid * 8])
#define SGL4(SB, T) do { SGL(SB,T,0); SGL(SB,T,1); SGL(SB,T,2); SGL(SB,T,3); } while (0)

// A fragment read (swizzled): M = m-frag idx, SWZ = precomputed kh-dependent xor offset
#define AF(RB, M, SWZ) (*(const bf16x8*)&Alds[RB][abase + (M) * 1024 + (SWZ)])

// One phase: {2 ds_read ; B-issue ; A-stage issue ; [vmcnt] ; barrier ; lgkm0 ; 10 MFMA ; barrier}
#define PH(RB, BC, SWZ, KH, M0, M1, HW, WN, BI, SI) do { \
    bf16x8 af0_ = AF(RB, M0, SWZ); \
    bf16x8 af1_ = AF(RB, M1, SWZ); \
    BI; \
    SI; \
    if (HW) WAITVM(WN); \
    BARRIER(); \
    WAITLGKM0(); \
    __builtin_amdgcn_sched_barrier(0); \
    __builtin_amdgcn_s_setprio(1); \
    acc[0][M0] = MF(af0_, BC[0 + (KH)], acc[0][M0]); \
    acc[0][M1] = MF(af1_, BC[0 + (KH)], acc[0][M1]); \
    acc[1][M0] = MF(af0_, BC[2 + (KH)], acc[1][M0]); \
    acc[1][M1] = MF(af1_, BC[2 + (KH)], acc[1][M1]); \
    acc[2][M0] = MF(af0_, BC[4 + (KH)], acc[2][M0]); \
    acc[2][M1] = MF(af1_, BC[4 + (KH)], acc[2][M1]); \
    acc[3][M0] = MF(af0_, BC[6 + (KH)], acc[3][M0]); \
    acc[3][M1] = MF(af1_, BC[6 + (KH)], acc[3][M1]); \
    acc[4][M0] = MF(af0_, BC[8 + (KH)], acc[4][M0]); \
    acc[4][M1] = MF(af1_, BC[8 + (KH)], acc[4][M1]); \
    __builtin_amdgcn_s_setprio(0); \
    BARRIER(); \
} while (0)

// steady-state tile: reads buf RB, stages A(TN+3) into SB, loads B(TN+1) into BN
#define TILE_FULL(TN, RB, SB, BC, BN) do { \
    PH(RB, BC, swz0, 0, 0, 1, 1, 10, LBA(BN, (TN) + 1), SGL(SB, (TN) + 3, 0)); \
    PH(RB, BC, swz0, 0, 2, 3, 0, 0,  LBB(BN, (TN) + 1), SGL(SB, (TN) + 3, 1)); \
    PH(RB, BC, swz1, 1, 0, 1, 1, 11, LBC(BN, (TN) + 1), SGL(SB, (TN) + 3, 2)); \
    PH(RB, BC, swz1, 1, 2, 3, 1, 28, LBD(BN, (TN) + 1), SGL(SB, (TN) + 3, 3)); \
} while (0)

__global__ __launch_bounds__(512, 2)
void xlstm_gemm(const unsigned short* __restrict__ A,
                const unsigned short* __restrict__ Bp,
                const float* __restrict__ bias,
                const float* __restrict__ c_prev,
                float* __restrict__ out) {
    __shared__ __align__(16) unsigned short Alds[4][BM * BK];  // 4 x 32 KB = 128 KB

    const int tid  = threadIdx.x;
    const int wid  = tid >> 6;
    const int lane = tid & 63;
    const int wm   = wid >> 1;    // 0..3 : M quarter (64 rows)
    const int wj   = wid & 1;     // 0..1 : j half (16 cols)
    const int fr   = lane & 15;
    const int q    = lane >> 4;

    // T1: bijective XCD swizzle (nwg = 1024, 1024 % 8 == 0)
    const int orig = blockIdx.x;
    const int wg   = (orig & 7) * 128 + (orig >> 3);
    const int mblk = wg >> 4;     // 0..63
    const int jblk = wg & 15;     // 0..15
    const long brow = (long)mblk * BM;
    const int  bcol = jblk * BNJ;
    const int  jgrp = jblk * 2 + wj;  // 0..31

    f32x4 acc[5][4];
#pragma unroll
    for (int g = 0; g < 5; ++g)
#pragma unroll
        for (int m = 0; m < 4; ++m)
#pragma unroll
            for (int r = 0; r < 4; ++r) acc[g][m][r] = 0.f;

    bf16x8 BA[10], BB[10];

    // per-thread precomputed addresses
    const int r0_ = tid >> 3;
    const long srcoff = (brow + r0_) * 1024L + (((tid & 7) ^ (r0_ & 7)) << 3);
    const unsigned short* bbase = Bp + (long)jgrp * 81920 + lane * 8;
    const int abase = (wm * 64 + fr) * 64;
    const int swz0 = ((q) ^ (fr & 7)) << 3;
    const int swz1 = ((4 | q) ^ (fr & 7)) << 3;

    // ---- prologue: A(0),A(1),A(2) staged; B(0) in regs; one-time full drain ----
    SGL4(0, 0); SGL4(1, 1); SGL4(2, 2);
    LBA(BA, 0); LBB(BA, 0); LBC(BA, 0); LBD(BA, 0);
    WAITVM(0);
    BARRIER();

    // ---- steady tiles 0..12 (stage A(T+3), load B(T+1)) ----
    for (int tq = 0; tq < 12; tq += 4) {
        TILE_FULL(tq + 0, 0, 3, BA, BB);
        TILE_FULL(tq + 1, 1, 0, BB, BA);
        TILE_FULL(tq + 2, 2, 1, BA, BB);
        TILE_FULL(tq + 3, 3, 2, BB, BA);
    }
    TILE_FULL(12, 0, 3, BA, BB);

    // ---- tail tiles 13,14,15 (tightened reorder-robust waits) ----
    // T=13: reads buf1, uses BB, loads B(14) into BA, no A-stage
    PH(1, BB, swz0, 0, 0, 1, 1, 9,  LBA(BA, 14), NOB());
    PH(1, BB, swz0, 0, 2, 3, 0, 0,  LBB(BA, 14), NOB());
    PH(1, BB, swz1, 1, 0, 1, 1, 8,  LBC(BA, 14), NOB());
    PH(1, BB, swz1, 1, 2, 3, 1, 24, LBD(BA, 14), NOB());
    // T=14: buf2, BA, loads B(15) into BB
    PH(2, BA, swz0, 0, 0, 1, 1, 7,  LBA(BB, 15), NOB());
    PH(2, BA, swz0, 0, 2, 3, 0, 0,  LBB(BB, 15), NOB());
    PH(2, BA, swz1, 1, 0, 1, 1, 8,  LBC(BB, 15), NOB());
    PH(2, BA, swz1, 1, 2, 3, 1, 20, LBD(BB, 15), NOB());
    // T=15: buf3, BB, nothing to issue
    PH(3, BB, swz0, 0, 0, 1, 1, 4,  NOB(), NOB());
    PH(3, BB, swz0, 0, 2, 3, 0, 0,  NOB(), NOB());
    PH(3, BB, swz1, 1, 0, 1, 1, 0,  NOB(), NOB());
    PH(3, BB, swz1, 1, 2, 3, 0, 0,  NOB(), NOB());

    // ---------------- epilogue (fused, in-register) ----------------
    const int j = bcol + wj * 16 + fr;
    const float bi_ = bias[j];
    const float bf_ = bias[512 + j];
    const float bc_ = bias[1024 + j];
    const float bo_ = bias[1536 + j];
    const float be_ = bias[2048 + j];
    const long mbase = brow + wm * 64 + (q << 2);
#pragma unroll
    for (int m = 0; m < 4; ++m) {
#pragma unroll
        for (int r = 0; r < 4; ++r) {
            long row = mbase + m * 16 + r;
            float gi = acc[0][m][r] + bi_;
            float gf = acc[1][m][r] + bf_;
            float gc = acc[2][m][r] + bc_;
            float go = acc[3][m][r] + bo_;
            float ge = acc[4][m][r] + be_;
            float iv = fast_sigmoid(gi);
            float fv = fast_sigmoid(gf);
            float gv = fast_tanh(gc);
            float ov = fast_sigmoid(go);
            float ef = __expf(fast_tanh(ge));
            float cp = c_prev[row * 512 + j];
            float cv = fv * cp + iv * gv;
            float hv = ov * fast_tanh(cv) * ef;
            out[row * 512 + j] = hv;
            out[(long)Bsz * 512 + row * 512 + j] = cv;
        }
    }
}

extern "C" void kernel_launch(void* const* d_in, const int* in_sizes, int n_in,
                              void* d_out, int out_size, void* d_ws, size_t ws_size,
                              hipStream_t stream) {
    const float* x      = (const float*)d_in[0];
    const float* h_prev = (const float*)d_in[1];
    const float* c_prev = (const float*)d_in[2];
    const float* Wxi = (const float*)d_in[3];
    const float* bxi = (const float*)d_in[4];
    const float* Whi = (const float*)d_in[5];
    const float* bhi = (const float*)d_in[6];
    const float* Wxf = (const float*)d_in[7];
    const float* bxf = (const float*)d_in[8];
    const float* Whf = (const float*)d_in[9];
    const float* bhf = (const float*)d_in[10];
    const float* Wxc = (const float*)d_in[11];
    const float* bxc = (const float*)d_in[12];
    const float* Whc = (const float*)d_in[13];
    const float* bhc = (const float*)d_in[14];
    const float* Wxo = (const float*)d_in[15];
    const float* bxo = (const float*)d_in[16];
    const float* Who = (const float*)d_in[17];
    const float* bho = (const float*)d_in[18];
    const float* We  = (const float*)d_in[19];
    const float* be  = (const float*)d_in[20];

    unsigned short* Abf  = (unsigned short*)d_ws;                        // 33,554,432 B
    unsigned short* Bp   = (unsigned short*)((char*)d_ws + 33554432);    //  5,242,880 B
    float*          bias = (float*)((char*)d_ws + 33554432 + 5242880);   //     10,240 B

    pack_A<<<2048, 256, 0, stream>>>(x, h_prev, Abf);
    pack_B<<<1280, 256, 0, stream>>>(Wxi, Whi, Wxf, Whf, Wxc, Whc, Wxo, Who, We,
                                     bxi, bhi, bxf, bhf, bxc, bhc, bxo, bho, be,
                                     Bp, bias);
    xlstm_gemm<<<1024, 512, 0, stream>>>(Abf, Bp, bias, c_prev, (float*)d_out);
}

// Round 4
// 129.189 us; speedup vs baseline: 1.1076x; 1.1076x over previous
//
#include <hip/hip_runtime.h>
#include <stdint.h>

#define Bsz 16384
#define Hh  512
#define Kd  1024      // I + H
#define BM  256       // M rows per workgroup
#define BNJ 32        // j columns per workgroup (x5 gates)
#define BK  64        // K per tile
#define NT  16        // K tiles

// LDS: 3 buffers x (A 32KB + B 20KB) = 156 KB
#define BUFB 53248

typedef __attribute__((ext_vector_type(8))) short bf16x8;
typedef __attribute__((ext_vector_type(4))) float f32x4;
typedef __attribute__((ext_vector_type(8))) unsigned short u16x8;

__device__ __forceinline__ unsigned short f2bf(float f) {
    union { float f; unsigned u; } v; v.f = f;
    unsigned u = v.u;
    return (unsigned short)((u + 0x7fffu + ((u >> 16) & 1u)) >> 16);
}
__device__ __forceinline__ float fast_tanh(float x) {
    float e = __expf(2.f * x);
    return (e - 1.f) / (e + 1.f);
}
__device__ __forceinline__ float fast_sigmoid(float x) {
    return 1.f / (1.f + __expf(-x));
}

// ---------------- pack A = [x | h_prev] -> bf16 [16384][1024] ----------------
__global__ void pack_A(const float* __restrict__ x, const float* __restrict__ h,
                       unsigned short* __restrict__ A) {
    const long total = (long)Bsz * Kd / 8;
    for (long i = (long)blockIdx.x * blockDim.x + threadIdx.x; i < total;
         i += (long)gridDim.x * blockDim.x) {
        long row = i >> 7;
        int  col = ((int)(i & 127)) << 3;
        const float* src = (col < 512) ? (x + row * 512 + col)
                                       : (h + row * 512 + (col - 512));
        float4 f0 = *(const float4*)(src);
        float4 f1 = *(const float4*)(src + 4);
        u16x8 o;
        o[0]=f2bf(f0.x); o[1]=f2bf(f0.y); o[2]=f2bf(f0.z); o[3]=f2bf(f0.w);
        o[4]=f2bf(f1.x); o[5]=f2bf(f1.y); o[6]=f2bf(f1.z); o[7]=f2bf(f1.w);
        *(u16x8*)(A + (i << 3)) = o;
    }
}

// ---- pack B into per-wave-fragment-linear layout ----
// elem addr = jgrp*81920 + g*16384 + kt*1024 + kh*512 + l*8 + e
//  = W[g][ j = jgrp*16 + (l&15) ][ k = kt*64 + kh*32 + (l>>4)*8 + e ]
__global__ void pack_B(const float* __restrict__ Wxi, const float* __restrict__ Whi,
                       const float* __restrict__ Wxf, const float* __restrict__ Whf,
                       const float* __restrict__ Wxc, const float* __restrict__ Whc,
                       const float* __restrict__ Wxo, const float* __restrict__ Who,
                       const float* __restrict__ We,
                       const float* __restrict__ bxi, const float* __restrict__ bhi,
                       const float* __restrict__ bxf, const float* __restrict__ bhf,
                       const float* __restrict__ bxc, const float* __restrict__ bhc,
                       const float* __restrict__ bxo, const float* __restrict__ bho,
                       const float* __restrict__ be,
                       unsigned short* __restrict__ Bp, float* __restrict__ bias) {
    const long id = (long)blockIdx.x * blockDim.x + threadIdx.x;  // 327680 total
    if (id < 327680) {
        int blk = (int)(id >> 6);
        int l   = (int)(id & 63);
        int kh  = blk & 1;
        int kt  = (blk >> 1) & 15;
        int rest = blk >> 5;
        int g    = rest % 5;
        int jgrp = rest / 5;
        int j  = jgrp * 16 + (l & 15);
        int k0 = kt * 64 + kh * 32 + ((l >> 4) << 3);
        const float* src;
        if (g == 4) {
            src = We + (long)j * 1024 + k0;
        } else {
            const float* Wx = (g == 0) ? Wxi : (g == 1) ? Wxf : (g == 2) ? Wxc : Wxo;
            const float* Wh = (g == 0) ? Whi : (g == 1) ? Whf : (g == 2) ? Whc : Who;
            src = (k0 < 512) ? (Wx + (long)j * 512 + k0)
                             : (Wh + (long)j * 512 + (k0 - 512));
        }
        float4 f0 = *(const float4*)(src);
        float4 f1 = *(const float4*)(src + 4);
        u16x8 o;
        o[0]=f2bf(f0.x); o[1]=f2bf(f0.y); o[2]=f2bf(f0.z); o[3]=f2bf(f0.w);
        o[4]=f2bf(f1.x); o[5]=f2bf(f1.y); o[6]=f2bf(f1.z); o[7]=f2bf(f1.w);
        *(u16x8*)(Bp + (long)blk * 512 + l * 8) = o;
    }
    if (id < 2560) {
        int row = (int)id;
        int g = row >> 9, j = row & 511;
        float b;
        if (g == 4) b = be[j];
        else {
            const float* bx = (g == 0) ? bxi : (g == 1) ? bxf : (g == 2) ? bxc : bxo;
            const float* bh = (g == 0) ? bhi : (g == 1) ? bhf : (g == 2) ? bhc : bho;
            b = bx[j] + bh[j];
        }
        bias[row] = b;
    }
}

// ---------------- fused GEMM (5-gate), A+B in LDS, 3-buffer counted-vmcnt ----------------
#define GL16(g, l) __builtin_amdgcn_global_load_lds( \
    (const __attribute__((address_space(1))) unsigned int*)(g), \
    (__attribute__((address_space(3))) unsigned int*)(l), 16, 0, 0)

#define WAITVM_I(n) asm volatile("s_waitcnt vmcnt(" #n ")" ::: "memory")
#define WAITVM(n) WAITVM_I(n)
#define WAITLGKM0() asm volatile("s_waitcnt lgkmcnt(0)" ::: "memory")
#define BARRIER() asm volatile("s_barrier" ::: "memory")
#define SCHED0() __builtin_amdgcn_sched_barrier(0)

#define MF(a, b, c) __builtin_amdgcn_mfma_f32_16x16x32_bf16(a, b, c, 0, 0, 0)

// stage slot I of tile TT into LDS buffer SBUF (one GL16, wave-uniform dest)
#define SGT(SBUF, TT, I) GL16(sb##I + (long)(TT) * sstr##I, \
    lds_raw + (SBUF) * BUFB + sld##I)

#define LOADB5(BUF, KH) do { \
    b0 = *(const bf16x8*)(lds_raw + (BUF)*BUFB + bbyte + 0*2048 + (KH)*1024); \
    b1 = *(const bf16x8*)(lds_raw + (BUF)*BUFB + bbyte + 1*2048 + (KH)*1024); \
    b2 = *(const bf16x8*)(lds_raw + (BUF)*BUFB + bbyte + 2*2048 + (KH)*1024); \
    b3 = *(const bf16x8*)(lds_raw + (BUF)*BUFB + bbyte + 3*2048 + (KH)*1024); \
    b4 = *(const bf16x8*)(lds_raw + (BUF)*BUFB + bbyte + 4*2048 + (KH)*1024); \
} while (0)

#define LOADA2(BUF, M0, M1, SWZ) do { \
    af0 = *(const bf16x8*)(lds_raw + (BUF)*BUFB + abyte + (M0)*2048 + (SWZ)); \
    af1 = *(const bf16x8*)(lds_raw + (BUF)*BUFB + abyte + (M1)*2048 + (SWZ)); \
} while (0)

#define MFMA10(M0, M1) do { \
    __builtin_amdgcn_s_setprio(1); \
    acc[0][M0] = MF(af0, b0, acc[0][M0]); acc[0][M1] = MF(af1, b0, acc[0][M1]); \
    acc[1][M0] = MF(af0, b1, acc[1][M0]); acc[1][M1] = MF(af1, b1, acc[1][M1]); \
    acc[2][M0] = MF(af0, b2, acc[2][M0]); acc[2][M1] = MF(af1, b2, acc[2][M1]); \
    acc[3][M0] = MF(af0, b3, acc[3][M0]); acc[3][M1] = MF(af1, b3, acc[3][M1]); \
    acc[4][M0] = MF(af0, b4, acc[4][M0]); acc[4][M1] = MF(af1, b4, acc[4][M1]); \
    __builtin_amdgcn_s_setprio(0); \
} while (0)

// 4 phases per K-tile; stage 7 chunks of tile T+2; one counted vmcnt(7) at ph3
#define TILE_STD(T, BUF, SBUF) do { \
    LOADB5(BUF, 0); LOADA2(BUF, 0, 1, swz0); \
    SGT(SBUF, (T)+2, 0); SGT(SBUF, (T)+2, 1); \
    BARRIER(); WAITLGKM0(); SCHED0(); MFMA10(0, 1); BARRIER(); \
    LOADA2(BUF, 2, 3, swz0); \
    SGT(SBUF, (T)+2, 2); SGT(SBUF, (T)+2, 3); \
    BARRIER(); WAITLGKM0(); SCHED0(); MFMA10(2, 3); BARRIER(); \
    LOADB5(BUF, 1); LOADA2(BUF, 0, 1, swz1); \
    SGT(SBUF, (T)+2, 4); SGT(SBUF, (T)+2, 5); \
    BARRIER(); WAITLGKM0(); SCHED0(); MFMA10(0, 1); BARRIER(); \
    LOADA2(BUF, 2, 3, swz1); \
    SGT(SBUF, (T)+2, 6); \
    WAITVM(7); \
    BARRIER(); WAITLGKM0(); SCHED0(); MFMA10(2, 3); BARRIER(); \
} while (0)

#define TILE_T14(BUF) do { \
    LOADB5(BUF, 0); LOADA2(BUF, 0, 1, swz0); \
    BARRIER(); WAITLGKM0(); SCHED0(); MFMA10(0, 1); BARRIER(); \
    LOADA2(BUF, 2, 3, swz0); \
    BARRIER(); WAITLGKM0(); SCHED0(); MFMA10(2, 3); BARRIER(); \
    LOADB5(BUF, 1); LOADA2(BUF, 0, 1, swz1); \
    BARRIER(); WAITLGKM0(); SCHED0(); MFMA10(0, 1); BARRIER(); \
    LOADA2(BUF, 2, 3, swz1); \
    WAITVM(0); \
    BARRIER(); WAITLGKM0(); SCHED0(); MFMA10(2, 3); BARRIER(); \
} while (0)

#define TILE_T15(BUF) do { \
    LOADB5(BUF, 0); LOADA2(BUF, 0, 1, swz0); \
    BARRIER(); WAITLGKM0(); SCHED0(); MFMA10(0, 1); BARRIER(); \
    LOADA2(BUF, 2, 3, swz0); \
    BARRIER(); WAITLGKM0(); SCHED0(); MFMA10(2, 3); BARRIER(); \
    LOADB5(BUF, 1); LOADA2(BUF, 0, 1, swz1); \
    BARRIER(); WAITLGKM0(); SCHED0(); MFMA10(0, 1); BARRIER(); \
    LOADA2(BUF, 2, 3, swz1); \
    BARRIER(); WAITLGKM0(); SCHED0(); MFMA10(2, 3); \
} while (0)

// init staging slot I (per wave: 7 slots; chunk c = wid*7+I, dups wrap to A chunks)
#define INIT_SLOT(I) do { \
    int c_ = wid * 7 + (I); if (c_ >= 52) c_ -= 52; \
    if (c_ < 32) { \
        sb##I   = A + (brow + 8 * c_ + (lane >> 3)) * 1024L \
                    + (((lane & 7) ^ ((lane >> 3) & 7)) << 3); \
        sstr##I = 64; \
        sld##I  = c_ * 1024; \
    } else { \
        int b_ = c_ - 32; int jl_ = b_ / 10; int rem_ = b_ - jl_ * 10; \
        sb##I   = Bp + (long)(jblk * 2 + jl_) * 81920 \
                    + (rem_ >> 1) * 16384 + (rem_ & 1) * 512 + lane * 8; \
        sstr##I = 1024; \
        sld##I  = 32768 + b_ * 1024; \
    } \
} while (0)

__global__ __launch_bounds__(512, 2)
void xlstm_gemm(const unsigned short* __restrict__ A,
                const unsigned short* __restrict__ Bp,
                const float* __restrict__ bias,
                const float* __restrict__ c_prev,
                float* __restrict__ out) {
    __shared__ __align__(16) unsigned char lds_raw[3 * BUFB];  // 156 KB

    const int tid  = threadIdx.x;
    const int wid  = tid >> 6;
    const int lane = tid & 63;
    const int wm   = wid >> 1;    // 0..3 : M quarter (64 rows)
    const int wj   = wid & 1;     // 0..1 : j half (16 cols)
    const int fr   = lane & 15;
    const int q    = lane >> 4;

    // T1: bijective XCD swizzle (nwg = 1024, 1024 % 8 == 0)
    const int orig = blockIdx.x;
    const int wg   = (orig & 7) * 128 + (orig >> 3);
    const int mblk = wg >> 4;     // 0..63
    const int jblk = wg & 15;     // 0..15
    const long brow = (long)mblk * BM;
    const int  bcol = jblk * BNJ;

    f32x4 acc[5][4];
#pragma unroll
    for (int g = 0; g < 5; ++g)
#pragma unroll
        for (int m = 0; m < 4; ++m)
#pragma unroll
            for (int r = 0; r < 4; ++r) acc[g][m][r] = 0.f;

    bf16x8 af0, af1, b0, b1, b2, b3, b4;

    // read-side addressing
    const int abyte = (wm * 64 + fr) * 128;               // A frag base (bytes)
    const int bbyte = 32768 + wj * 10240 + lane * 16;     // B frag base (bytes)
    const int swz0  = ((q) ^ (fr & 7)) << 4;
    const int swz1  = ((4 | q) ^ (fr & 7)) << 4;

    // staging slots
    const unsigned short *sb0, *sb1, *sb2, *sb3, *sb4, *sb5, *sb6;
    int sstr0, sstr1, sstr2, sstr3, sstr4, sstr5, sstr6;
    int sld0, sld1, sld2, sld3, sld4, sld5, sld6;
    INIT_SLOT(0); INIT_SLOT(1); INIT_SLOT(2); INIT_SLOT(3);
    INIT_SLOT(4); INIT_SLOT(5); INIT_SLOT(6);

    // ---- prologue: stage tile 0 -> buf 0, tile 1 -> buf 1; certify tile 0 ----
    SGT(0, 0, 0); SGT(0, 0, 1); SGT(0, 0, 2); SGT(0, 0, 3);
    SGT(0, 0, 4); SGT(0, 0, 5); SGT(0, 0, 6);
    SGT(1, 1, 0); SGT(1, 1, 1); SGT(1, 1, 2); SGT(1, 1, 3);
    SGT(1, 1, 4); SGT(1, 1, 5); SGT(1, 1, 6);
    WAITVM(7);
    BARRIER();

    // ---- main loop: tile t reads buf t%3, stages t+2 into buf (t+2)%3 ----
    for (int t = 0; t < 12; t += 3) {
        TILE_STD(t,     0, 2);
        TILE_STD(t + 1, 1, 0);
        TILE_STD(t + 2, 2, 1);
    }
    TILE_STD(12, 0, 2);
    TILE_STD(13, 1, 0);
    TILE_T14(2);
    TILE_T15(0);

    // ---------------- epilogue (fused, in-register) ----------------
    const int j = bcol + wj * 16 + fr;
    const float bi_ = bias[j];
    const float bf_ = bias[512 + j];
    const float bc_ = bias[1024 + j];
    const float bo_ = bias[1536 + j];
    const float be_ = bias[2048 + j];
    const long mbase = brow + wm * 64 + (q << 2);
#pragma unroll
    for (int m = 0; m < 4; ++m) {
#pragma unroll
        for (int r = 0; r < 4; ++r) {
            long row = mbase + m * 16 + r;
            float gi = acc[0][m][r] + bi_;
            float gf = acc[1][m][r] + bf_;
            float gc = acc[2][m][r] + bc_;
            float go = acc[3][m][r] + bo_;
            float ge = acc[4][m][r] + be_;
            float iv = fast_sigmoid(gi);
            float fv = fast_sigmoid(gf);
            float gv = fast_tanh(gc);
            float ov = fast_sigmoid(go);
            float ef = __expf(fast_tanh(ge));
            float cp = c_prev[row * 512 + j];
            float cv = fv * cp + iv * gv;
            float hv = ov * fast_tanh(cv) * ef;
            out[row * 512 + j] = hv;
            out[(long)Bsz * 512 + row * 512 + j] = cv;
        }
    }
}

extern "C" void kernel_launch(void* const* d_in, const int* in_sizes, int n_in,
                              void* d_out, int out_size, void* d_ws, size_t ws_size,
                              hipStream_t stream) {
    const float* x      = (const float*)d_in[0];
    const float* h_prev = (const float*)d_in[1];
    const float* c_prev = (const float*)d_in[2];
    const float* Wxi = (const float*)d_in[3];
    const float* bxi = (const float*)d_in[4];
    const float* Whi = (const float*)d_in[5];
    const float* bhi = (const float*)d_in[6];
    const float* Wxf = (const float*)d_in[7];
    const float* bxf = (const float*)d_in[8];
    const float* Whf = (const float*)d_in[9];
    const float* bhf = (const float*)d_in[10];
    const float* Wxc = (const float*)d_in[11];
    const float* bxc = (const float*)d_in[12];
    const float* Whc = (const float*)d_in[13];
    const float* bhc = (const float*)d_in[14];
    const float* Wxo = (const float*)d_in[15];
    const float* bxo = (const float*)d_in[16];
    const float* Who = (const float*)d_in[17];
    const float* bho = (const float*)d_in[18];
    const float* We  = (const float*)d_in[19];
    const float* be  = (const float*)d_in[20];

    unsigned short* Abf  = (unsigned short*)d_ws;                        // 33,554,432 B
    unsigned short* Bp   = (unsigned short*)((char*)d_ws + 33554432);    //  5,242,880 B
    float*          bias = (float*)((char*)d_ws + 33554432 + 5242880);   //     10,240 B

    pack_A<<<2048, 256, 0, stream>>>(x, h_prev, Abf);
    pack_B<<<1280, 256, 0, stream>>>(Wxi, Whi, Wxf, Whf, Wxc, Whc, Wxo, Who, We,
                                     bxi, bhi, bxf, bhf, bxc, bhc, bxo, bho, be,
                                     Bp, bias);
    xlstm_gemm<<<1024, 512, 0, stream>>>(Abf, Bp, bias, c_prev, (float*)d_out);
}